// Round 13
// baseline (279.296 us; speedup 1.0000x reference)
//
#include <hip/hip_runtime.h>
#include <hip/hip_bf16.h>
#include <hip/hip_fp8.h>

// ---------------------------------------------------------------------------
// GRACE contrastive loss, MI355X.
//  out = mean_k 0.5*(ln d1_k + ln d2_k) - 2*s12[k,k]
// S symmetric -> upper-triangle 128x128 tiles, row+col sums per tile.
//
// R19: PRODUCER/CONSUMER WAVE SPECIALIZATION in sim. Cycle model of R13
// (per SIMD over 125us): matrix 80K cy, VALU+trans 113K (74K = the exps
// alone), idle 114K. matrix ~= exp work, so concurrent pipes => ~45-55us.
// Intra-wave interleave is proven dead (R10/R11); cross-block statistical
// overlap never materializes. The one HW-proven overlap is DIFFERENT
// waves on different pipes (m114). So: 512-thr blocks, waves 0-3 = MFMA
// producers (R13's exact MFMA+staging, no exp), waves 4-7 = exp consumers
// (read raw acc from LDS, exp + rs/cs + probes + flushes, no MFMA).
// w%4 SIMD round-robin pairs 1 producer + 1 consumer per SIMD. Exchange:
// Ab[2][quad][64x32 f32] half-tile ping-pong (2x32KB), producer lane l
// writes its acc f32x4s, consumer lane l reads the same slot -> all R13
// index math carries over verbatim. 1 barrier per half-tile. LDS 128KB ->
// 1 block/CU (8 waves = 2/SIMD); grid 768 = 96 pairs x 8 slots (24-25
// tiles), 3 rounds. Producer live set ~100 regs < ~124 cap at (512,2).
// Tripwire: VGPR<=90 + WRITE>>26MB = spill; dur~125 = pairing failed.
// mlp/cast/finalize = R18 verbatim.
// ---------------------------------------------------------------------------

#define NROWS 12288
#define TWO_N 24576
#define KDIM 256
#define BM 128
#define BK 32
#define NTILE 192   /* 24576 / 128 row-tiles */
#define PAIRS 96
#define FB 48                   /* finalize partial blocks */
#define LOG2E 1.4426950408889634f
#define SIMSCALE 1.6986436f     /* sqrt(2*log2(e)); acc = (1/tau)*log2e*s */
#define LN2F 0.6931471805599453f

#if __has_builtin(__builtin_amdgcn_exp2f)
#define EXP2F(x) __builtin_amdgcn_exp2f(x)
#else
#define EXP2F(x) exp2f(x)
#endif

typedef __bf16 bf16x8 __attribute__((ext_vector_type(8)));
typedef __bf16 bf16x4v __attribute__((ext_vector_type(4)));
typedef float f32x4 __attribute__((ext_vector_type(4)));
typedef int i32x4 __attribute__((ext_vector_type(4)));
typedef int i32x8 __attribute__((ext_vector_type(8)));
typedef unsigned char uchar;

typedef const __attribute__((address_space(1))) void* gptr_t;
typedef __attribute__((address_space(3))) void* lptr_t;

// read MFMA A/B fragment from a [rows x 32] LDS slab with the XOR swizzle
__device__ __forceinline__ bf16x8 read_frag(const __bf16* lds, int rowbase,
                                            int tile, int l) {
  int r = rowbase + tile * 16 + (l & 15);
  int q = l >> 4;
  int blk = q ^ (r & 3);
  return *(const bf16x8*)(lds + r * 32 + blk * 8);
}

// ---------------------------------------------------------------------------
// cast W1, W2 to bf16 (z is consumed f32 directly by mlp_kernel)
__global__ void cast_w_kernel(const float* __restrict__ W1,
                              const float* __restrict__ W2,
                              __bf16* __restrict__ W1b,
                              __bf16* __restrict__ W2b) {
  const int n4w = KDIM * KDIM / 4;   // 16384
  int i = blockIdx.x * blockDim.x + threadIdx.x;
  const float* src;
  __bf16* dst;
  int j;
  if (i < n4w) {
    src = W1; dst = W1b; j = i;
  } else if (i < 2 * n4w) {
    src = W2; dst = W2b; j = i - n4w;
  } else {
    return;
  }
  float4 v = *(const float4*)(src + (size_t)j * 4);
  bf16x4v o;
  o[0] = (__bf16)v.x; o[1] = (__bf16)v.y; o[2] = (__bf16)v.z; o[3] = (__bf16)v.w;
  *(bf16x4v*)(dst + (size_t)j * 4) = o;
}

// fp8 e4m3 byte via the HW cvt
__device__ __forceinline__ uchar fp8_byte(float x) {
#if __has_builtin(__builtin_amdgcn_cvt_pk_fp8_f32)
  int v = __builtin_amdgcn_cvt_pk_fp8_f32(x, 0.f, 0, false);
  return (uchar)(v & 0xFF);
#else
  __hip_fp8_e4m3 qv(x);
  return qv.__x;
#endif
}

// ======== R18 fused MLP: z -> T(LDS) -> H(regs) -> Nq (verbatim) ===========
__global__ __launch_bounds__(256, 2) void mlp_kernel(
    const float* __restrict__ z1, const float* __restrict__ z2,
    const __bf16* __restrict__ W1b, const __bf16* __restrict__ W2b,
    const float* __restrict__ b1, const float* __restrict__ b2,
    uchar* __restrict__ Nq) {
  __shared__ __align__(16) __bf16 Zs[64 * BK];       // 4 KB
  __shared__ __align__(16) __bf16 Ws[KDIM * BK];     // 16 KB
  __shared__ __align__(16) __bf16 Ts[8 * 64 * 32];   // 32 KB (8 ks-slabs)
  __shared__ float ssred[4][64];                     // 1 KB
  __shared__ float invred[64];
  uchar* qbuf = (uchar*)Ts;  // Ts dead after GEMM2; 16 KB reused
  int tid = threadIdx.x;
  int w = tid >> 6, l = tid & 63;
  int q = l >> 4, rx = l & 15;
  int i0 = blockIdx.x * 64;
  int wbcol = w * 64;
  const float* zrow = (i0 < NROWS) ? (z1 + (size_t)i0 * KDIM)
                                   : (z2 + (size_t)(i0 - NROWS) * KDIM);

  auto stageW = [&](const __bf16* Wb, int ks) {
#pragma unroll
    for (int t = 0; t < 4; ++t) {
      int c = w * 4 + t;
      int rr = l >> 2, c2 = l & 3;
      int r = c * 16 + rr;
      int src = c2 ^ (r & 3);
      const __bf16* ga = Wb + (size_t)r * KDIM + ks * BK + src * 8;
      __builtin_amdgcn_global_load_lds((gptr_t)ga, (lptr_t)(Ws + c * 512),
                                       16, 0, 0);
    }
  };
  const int zr = tid >> 2, zblk = tid & 3;
  const int zsrc = zblk ^ (zr & 3);
  auto loadZ = [&](int ks, float4& v0, float4& v1) {
    const float* zp = zrow + (size_t)zr * KDIM + ks * BK + zsrc * 8;
    v0 = *(const float4*)zp;
    v1 = *(const float4*)(zp + 4);
  };

  f32x4 acc[4][4] = {};
  float4 zv0, zv1;
  loadZ(0, zv0, zv1);
  for (int ks = 0; ks < 8; ++ks) {
    __syncthreads();
    bf16x8 zo;
    zo[0] = (__bf16)zv0.x; zo[1] = (__bf16)zv0.y;
    zo[2] = (__bf16)zv0.z; zo[3] = (__bf16)zv0.w;
    zo[4] = (__bf16)zv1.x; zo[5] = (__bf16)zv1.y;
    zo[6] = (__bf16)zv1.z; zo[7] = (__bf16)zv1.w;
    *(bf16x8*)(Zs + zr * 32 + zblk * 8) = zo;
    stageW(W1b, ks);
    if (ks + 1 < 8) loadZ(ks + 1, zv0, zv1);
    __syncthreads();
    bf16x8 aF[4], bF[4];
#pragma unroll
    for (int mi = 0; mi < 4; ++mi) aF[mi] = read_frag(Zs, 0, mi, l);
#pragma unroll
    for (int ni = 0; ni < 4; ++ni) bF[ni] = read_frag(Ws, wbcol, ni, l);
#pragma unroll
    for (int mi = 0; mi < 4; ++mi)
#pragma unroll
      for (int ni = 0; ni < 4; ++ni)
        acc[mi][ni] = __builtin_amdgcn_mfma_f32_16x16x32_bf16(
            aF[mi], bF[ni], acc[mi][ni], 0, 0, 0);
  }

  float bias1[4];
#pragma unroll
  for (int ni = 0; ni < 4; ++ni) bias1[ni] = b1[wbcol + ni * 16 + rx];
#pragma unroll
  for (int mi = 0; mi < 4; ++mi)
#pragma unroll
    for (int ni = 0; ni < 4; ++ni)
#pragma unroll
      for (int v = 0; v < 4; ++v) {
        int row = mi * 16 + q * 4 + v;
        int col = wbcol + ni * 16 + rx;
        float x = acc[mi][ni][v] + bias1[ni];
        x = x > 0.f ? x : (EXP2F(x * LOG2E) - 1.f);  // ELU
        int ks2 = col >> 5, c32 = col & 31;
        Ts[ks2 * 2048 + row * 32 + (((c32 >> 3) ^ (row & 3)) << 3) +
           (col & 7)] = (__bf16)x;
      }

#pragma unroll
  for (int mi = 0; mi < 4; ++mi)
#pragma unroll
    for (int ni = 0; ni < 4; ++ni) acc[mi][ni] = (f32x4){0.f, 0.f, 0.f, 0.f};
  for (int ks = 0; ks < 8; ++ks) {
    __syncthreads();
    stageW(W2b, ks);
    __syncthreads();
    bf16x8 aF[4], bF[4];
#pragma unroll
    for (int mi = 0; mi < 4; ++mi)
      aF[mi] = read_frag(Ts + ks * 2048, 0, mi, l);
#pragma unroll
    for (int ni = 0; ni < 4; ++ni) bF[ni] = read_frag(Ws, wbcol, ni, l);
#pragma unroll
    for (int mi = 0; mi < 4; ++mi)
#pragma unroll
      for (int ni = 0; ni < 4; ++ni)
        acc[mi][ni] = __builtin_amdgcn_mfma_f32_16x16x32_bf16(
            aF[mi], bF[ni], acc[mi][ni], 0, 0, 0);
  }

  float bias2[4];
#pragma unroll
  for (int ni = 0; ni < 4; ++ni) bias2[ni] = b2[wbcol + ni * 16 + rx];
  float ss[4][4] = {};
#pragma unroll
  for (int mi = 0; mi < 4; ++mi)
#pragma unroll
    for (int ni = 0; ni < 4; ++ni)
#pragma unroll
      for (int v = 0; v < 4; ++v) {
        float x = acc[mi][ni][v] + bias2[ni];
        acc[mi][ni][v] = x;
        ss[mi][v] += x * x;
      }
#pragma unroll
  for (int mi = 0; mi < 4; ++mi)
#pragma unroll
    for (int v = 0; v < 4; ++v) {
      float x = ss[mi][v];
      x += __shfl_xor(x, 1, 64);
      x += __shfl_xor(x, 2, 64);
      x += __shfl_xor(x, 4, 64);
      x += __shfl_xor(x, 8, 64);
      if (rx == 0) ssred[w][mi * 16 + q * 4 + v] = x;
    }
  __syncthreads();
  if (tid < 64)
    invred[tid] = rsqrtf(ssred[0][tid] + ssred[1][tid] + ssred[2][tid] +
                         ssred[3][tid]) * SIMSCALE;
  __syncthreads();

#pragma unroll
  for (int mi = 0; mi < 4; ++mi)
#pragma unroll
    for (int v = 0; v < 4; ++v) {
      int row = mi * 16 + q * 4 + v;
      float iv = invred[row];
#pragma unroll
      for (int ni = 0; ni < 4; ++ni)
        qbuf[row * KDIM + wbcol + ni * 16 + rx] =
            fp8_byte(acc[mi][ni][v] * iv);
    }
  __syncthreads();
  size_t base = (size_t)i0 * KDIM;
#pragma unroll
  for (int it = 0; it < 8; ++it) {
    int idx = it * 2048 + tid * 8;
    *(uint2*)(Nq + base + idx) = *(const uint2*)(qbuf + idx);
  }
}

// ======== R19 sim kernel: producer/consumer wave specialization ============
// 512 thr = 8 waves. Waves 0-3: MFMA producers (quadrant wq = w&3 of the
// 128x128 tile: rows (wq>>1)*64, cols (wq&1)*64). Waves 4-7: exp consumers
// (same quadrant map). Exchange: Ab[2][4][512] float4 half-tile ping-pong;
// producer lane l writes acc f32x4 at (njh*4+mi)*64+l, consumer lane l
// reads the same slot -> R13 index math identical. One barrier/half-tile.
// Producers: Bs staging + aF + MFMA only. Consumers: exp + rs/cs + probes.
__global__ __launch_bounds__(512, 2) void sim_kernel(
    const uchar* __restrict__ Nq, float* __restrict__ Rlow,
    float* __restrict__ Rhigh, float* __restrict__ Dsame,
    float* __restrict__ Dcross) {
  __shared__ __align__(16) uchar Bs[2][BM * KDIM];   // 2 x 32KB
  __shared__ __align__(16) float4 Ab[2][4][512];     // 2 x 32KB
  int tid = threadIdx.x;
  int w = tid >> 6, l = tid & 63;
  bool prod = (w < 4);
  int wq = w & 3;              // quadrant id
  int q = l >> 4;
  int rx = l & 15;
  int b = blockIdx.x;
  int p = b >> 3;              // pair index 0..95
  int s = b & 7;               // slot within pair 0..7
  const int I1 = p, I2 = NTILE - 1 - p;
  const int L1 = NTILE - I1;   // seg1 length
  int fstart = (s == 0) ? 0 : 25 + (s - 1) * 24;
  int fend = fstart + ((s == 0) ? 25 : 24);
  const int T = fend - fstart;
  int warow = (wq >> 1) * 64;  // A rows of this quadrant
  int wbcol = (wq & 1) * 64;   // B cols of this quadrant

  auto jtile_of = [&](int F) { return (F < L1) ? (I1 + F) : (F - 1); };
  auto atile_of = [&](int F) { return (F < L1) ? I1 : I2; };

  // producer staging offsets (XOR swizzle), waves 0-3 cover 32 chunks
  unsigned off0[8];
#pragma unroll
  for (int t = 0; t < 8; ++t) {
    int ch = wq * 8 + t;
    int r = ch * 4 + q;
    int src = rx ^ (r & 15);
    off0[t] = (unsigned)(r * KDIM + src * 16);
  }
  auto stage = [&](int F, int bi) {
    unsigned jo = (unsigned)(jtile_of(F) * (BM * KDIM));
#pragma unroll
    for (int t = 0; t < 8; ++t) {
      const uchar* ga = Nq + (size_t)(jo + off0[t]);
      uchar* la = Bs[bi] + (wq * 8 + t) * 1024;
      __builtin_amdgcn_global_load_lds((gptr_t)ga, (lptr_t)la, 16, 0, 0);
    }
  };

  // ---- producer state ----
  i32x8 aF[4][2];
  auto load_aF = [&](int Atile) {
#pragma unroll
    for (int mi = 0; mi < 4; ++mi) {
      const uchar* ap = Nq +
          (size_t)(Atile * BM + warow + mi * 16 + rx) * KDIM + q * 32;
#pragma unroll
      for (int hf = 0; hf < 2; ++hf)
        aF[mi][hf] = *(const i32x8*)(ap + hf * 128);
    }
  };
  int rdo[2][2];
#pragma unroll
  for (int hf = 0; hf < 2; ++hf) {
    int kb = hf * 8 + 2 * q;
    rdo[hf][0] = (kb ^ rx) << 4;
    rdo[hf][1] = ((kb + 1) ^ rx) << 4;
  }
  const f32x4 Z4 = {0.f, 0.f, 0.f, 0.f};

  // produce half-tile ht (global within this block's window): 2 nj, 16 MFMA
  auto produce = [&](int ht) {
    int fl = ht >> 1;                       // local tile index
    int njbase = (ht & 1) * 2;
    const uchar* bL = Bs[fl & 1] + (size_t)(wbcol + rx) * KDIM;
#pragma unroll
    for (int njh = 0; njh < 2; ++njh) {
      const int no = (njbase + njh) * 4096;
      i32x8 bF0 = __builtin_shufflevector(
          *(const i32x4*)(bL + no + rdo[0][0]),
          *(const i32x4*)(bL + no + rdo[0][1]), 0, 1, 2, 3, 4, 5, 6, 7);
      i32x8 bF1 = __builtin_shufflevector(
          *(const i32x4*)(bL + no + rdo[1][0]),
          *(const i32x4*)(bL + no + rdo[1][1]), 0, 1, 2, 3, 4, 5, 6, 7);
      f32x4 acc[4];
#pragma unroll
      for (int mi = 0; mi < 4; ++mi)
        acc[mi] = __builtin_amdgcn_mfma_scale_f32_16x16x128_f8f6f4(
            aF[mi][0], bF0, Z4, 0, 0, 0, 0x7F7F7F7F, 0, 0x7F7F7F7F);
#pragma unroll
      for (int mi = 0; mi < 4; ++mi)
        acc[mi] = __builtin_amdgcn_mfma_scale_f32_16x16x128_f8f6f4(
            aF[mi][1], bF1, acc[mi], 0, 0, 0, 0x7F7F7F7F, 0, 0x7F7F7F7F);
#pragma unroll
      for (int mi = 0; mi < 4; ++mi)
        Ab[ht & 1][wq][(njh * 4 + mi) * 64 + l] =
            (float4){acc[mi][0], acc[mi][1], acc[mi][2], acc[mi][3]};
    }
  };

  // ---- consumer state ----
  f32x4 rs4[4] = {};
  f32x4 cs4[4];
  int pend = 0;
  float* pendR = nullptr;
  int pendBase = 0;
  int Aprev = atile_of(fstart);
  int hprev = (jtile_of(fstart) >= NTILE / 2) ? 1 : 0;

  auto flushrs = [&](int Atile, int h) {
    float* R = h ? Rhigh : Rlow;
#pragma unroll
    for (int mi = 0; mi < 4; ++mi)
#pragma unroll
      for (int v = 0; v < 4; ++v) {
        float x = rs4[mi][v];
        x += __shfl_xor(x, 1, 64);
        x += __shfl_xor(x, 2, 64);
        x += __shfl_xor(x, 4, 64);
        x += __shfl_xor(x, 8, 64);
        if (rx == 0)
          atomicAdd(&R[Atile * BM + warow + mi * 16 + q * 4 + v], x);
        rs4[mi][v] = 0.f;
      }
  };
  auto flushcs = [&]() {
#pragma unroll
    for (int nj = 0; nj < 4; ++nj) {
      float c = (cs4[nj][0] + cs4[nj][1]) + (cs4[nj][2] + cs4[nj][3]);
      c += __shfl_xor(c, 16, 64);
      c += __shfl_xor(c, 32, 64);
      if (q == 0)
        atomicAdd(&pendR[pendBase + wbcol + nj * 16 + rx], c);
    }
    pend = 0;
  };

  // consume half-tile g: exp + rs/cs + probes for tile fstart+(g>>1)
  auto consume = [&](int g) {
    int fl = g >> 1;
    int f = fstart + fl;
    int half = g & 1;
    int Atile = atile_of(f);
    int Jt = jtile_of(f);
    bool dsame = (Jt == Atile);
    bool dcross = (Jt == Atile + NTILE / 2);
    if (half == 0) {
      int h = (Jt >= NTILE / 2) ? 1 : 0;
      if (pend) flushcs();
      if (Atile != Aprev) {
        flushrs(Aprev, hprev);
        Aprev = Atile;
        hprev = h;
      } else if (h != hprev) {
        flushrs(Aprev, hprev);
        hprev = h;
      }
    }
#pragma unroll
    for (int njh = 0; njh < 2; ++njh) {
      int nj = half * 2 + njh;
      f32x4 e4sum = {0.f, 0.f, 0.f, 0.f};
#pragma unroll
      for (int mi = 0; mi < 4; ++mi) {
        float4 a = Ab[g & 1][wq][(njh * 4 + mi) * 64 + l];
        if (dsame | dcross) {          // wave-uniform, rare
          float* D = dsame ? Dsame : Dcross;
#pragma unroll
          for (int v = 0; v < 4; ++v) {
            int li = warow + mi * 16 + q * 4 + v;
            int lj = wbcol + nj * 16 + rx;
            float av = (v == 0) ? a.x : (v == 1) ? a.y : (v == 2) ? a.z : a.w;
            if (li == lj) D[Atile * BM + li] = av;
          }
        }
        f32x4 e4;
        e4[0] = EXP2F(a.x);
        e4[1] = EXP2F(a.y);
        e4[2] = EXP2F(a.z);
        e4[3] = EXP2F(a.w);
        rs4[mi] += e4;
        e4sum += e4;
      }
      cs4[nj] = (half == 0 && njh == 0 && false) ? e4sum : e4sum;  // set below
      cs4[nj] = e4sum;
    }
    if (half == 1 && !dsame) {   // schedule cs flush at next tile boundary
      pend = 1;
      pendR = (Atile >= NTILE / 2) ? Rhigh : Rlow;
      pendBase = Jt * BM;
    }
  };

  // ---- prologue ----
  if (prod) stage(fstart, 0);
  __syncthreads();                     // Bs[0] ready
  if (prod) {
    load_aF(atile_of(fstart));
    produce(0);                        // half 0 of first tile -> Ab[0]
    if (T > 1) stage(fstart + 1, 1);   // drains at next barrier
  }

  // ---- main loop: one barrier per half-tile ----
  for (int g = 0; g < 2 * T; ++g) {
    __syncthreads();                   // Ab[g&1] ready; stage drained
    int ht = g + 1;
    if (prod) {
      if (ht < 2 * T) {
        int fl = ht >> 1;
        if ((ht & 1) == 0) {           // entering local tile fl
          int At = atile_of(fstart + fl);
          int Ap = atile_of(fstart + fl - 1);
          if (At != Ap) load_aF(At);
          if (fl + 1 < T) stage(fstart + fl + 1, (fl + 1) & 1);
        }
        produce(ht);
      }
    } else {
      consume(g);
    }
  }

  // ---- epilogue (consumers) ----
  if (!prod) {
    if (pend) flushcs();
    flushrs(Aprev, hprev);
  }
}

// Dsame/Dcross hold acc = (1/tau)*log2e * s. exp(s/tau) = exp2(acc);
// -2*s = -ln2 * acc.  48 blocks x 256 threads = 12288 rows exactly.
__global__ void finalize1_kernel(const float* __restrict__ Rlow,
                                 const float* __restrict__ Rhigh,
                                 const float* __restrict__ Dsame,
                                 const float* __restrict__ Dcross,
                                 float* __restrict__ partial) {
  __shared__ float red[256];
  int k = blockIdx.x * 256 + threadIdx.x;
  float d1 = Rlow[k] + Rhigh[k] - EXP2F(Dsame[k]);
  float d2 = Rhigh[NROWS + k] + Rlow[NROWS + k] - EXP2F(Dsame[NROWS + k]);
  float acc = 0.5f * (logf(d1) + logf(d2)) - LN2F * Dcross[k];
  red[threadIdx.x] = acc;
  __syncthreads();
  for (int s = 128; s > 0; s >>= 1) {
    if (threadIdx.x < s) red[threadIdx.x] += red[threadIdx.x + s];
    __syncthreads();
  }
  if (threadIdx.x == 0) partial[blockIdx.x] = red[0];
}

__global__ void finalize2_kernel(const float* __restrict__ partial,
                                 float* __restrict__ out) {
  float x = (threadIdx.x < FB) ? partial[threadIdx.x] : 0.f;
#pragma unroll
  for (int s = 32; s > 0; s >>= 1) x += __shfl_down(x, s, 64);
  if (threadIdx.x == 0) out[0] = x / (float)NROWS;
}

// ---------------------------------------------------------------------------
extern "C" void kernel_launch(void* const* d_in, const int* in_sizes, int n_in,
                              void* d_out, int out_size, void* d_ws,
                              size_t ws_size, hipStream_t stream) {
  const float* z1 = (const float*)d_in[0];
  const float* z2 = (const float*)d_in[1];
  const float* W1 = (const float*)d_in[2];
  const float* b1 = (const float*)d_in[3];
  const float* W2 = (const float*)d_in[4];
  const float* b2 = (const float*)d_in[5];
  float* out = (float*)d_out;

  char* ws = (char*)d_ws;
  size_t off = 0;
  auto alloc = [&](size_t bytes) -> void* {
    void* p = ws + off;
    off += (bytes + 255) & ~(size_t)255;
    return p;
  };
  __bf16* W1b  = (__bf16*)alloc((size_t)KDIM * KDIM * 2);
  __bf16* W2b  = (__bf16*)alloc((size_t)KDIM * KDIM * 2);
  uchar*  Nq   = (uchar*)alloc((size_t)TWO_N * KDIM);
  float*  Rlow = (float*)alloc((size_t)TWO_N * 4);   // Rlow+Rhigh contiguous
  float*  Rhigh= (float*)alloc((size_t)TWO_N * 4);
  float*  Dsame= (float*)alloc((size_t)TWO_N * 4);
  float*  Dcross=(float*)alloc((size_t)NROWS * 4);
  float*  partial=(float*)alloc((size_t)FB * 4);

  hipMemsetAsync(Rlow, 0, (size_t)2 * TWO_N * 4, stream);

  int n4w = KDIM * KDIM / 4;    // 16384
  cast_w_kernel<<<(2 * n4w + 255) / 256, 256, 0, stream>>>(W1, W2, W1b, W2b);

  mlp_kernel<<<TWO_N / 64, 256, 0, stream>>>(z1, z2, W1b, W2b, b1, b2, Nq);

  sim_kernel<<<PAIRS * 8, 512, 0, stream>>>(Nq, Rlow, Rhigh, Dsame, Dcross);
  finalize1_kernel<<<FB, 256, 0, stream>>>(Rlow, Rhigh, Dsame, Dcross, partial);
  finalize2_kernel<<<1, 64, 0, stream>>>(partial, out);
}

// Round 14
// 202.047 us; speedup vs baseline: 1.3823x; 1.3823x over previous
//
#include <hip/hip_runtime.h>
#include <hip/hip_bf16.h>
#include <hip/hip_fp8.h>

// ---------------------------------------------------------------------------
// GRACE contrastive loss, MI355X.
//  out = mean_k 0.5*(ln d1_k + ln d2_k) - 2*s12[k,k]
// S symmetric -> upper-triangle tiles, row+col sums per tile (R12),
// col-sums deferred one tile (R13).
//
// R20: 4 INDEPENDENT BLOCKS PER CU. R19 (producer/consumer) failed: 1
// block/CU lockstep + LDS round-trip. The untested cell of the occupancy
// matrix is 4 waves/SIMD each from a DIFFERENT block (m114's config).
// R8 aimed at 3 and was invalidated by (256,3)'s 84-reg cap; (256,2)
// caps at ~124 and R13's core needs ~105. So: halve the J-tile to 64
// cols -> Bs 2x16KB = 32KB/block -> LDS admits 5 blocks, VGPR admits 4
// -> 4 blocks/CU, every SIMD gets 4 waves from 4 different blocks at
// unsynced phases. Wave = 32 A-rows x all 64 J-cols (aF[2][2] = 32 regs,
// LESS pressure than R13). G-tiles = R13's F split in half; gstart even
// so diag tiles stay within a slot. Col-sums: 4 contributions/col
// (WRITE +18MB, immaterial at 5% HBM). All other R13 logic verbatim.
// mlp/cast/finalize = R18 verbatim.
// Tripwire: VGPR<=90 + WRITE>>50MB = spill; occ ~20% = residency failed;
// occ ~40% + MfmaUtil ~26% = structure floor -> accept next round.
// ---------------------------------------------------------------------------

#define NROWS 12288
#define TWO_N 24576
#define KDIM 256
#define BM 128
#define BK 32
#define NTILE 192   /* 24576 / 128 row-tiles */
#define PAIRS 96
#define SLOTS 16
#define FB 48                   /* finalize partial blocks */
#define LOG2E 1.4426950408889634f
#define SIMSCALE 1.6986436f     /* sqrt(2*log2(e)); acc = (1/tau)*log2e*s */
#define LN2F 0.6931471805599453f

#if __has_builtin(__builtin_amdgcn_exp2f)
#define EXP2F(x) __builtin_amdgcn_exp2f(x)
#else
#define EXP2F(x) exp2f(x)
#endif

typedef __bf16 bf16x8 __attribute__((ext_vector_type(8)));
typedef __bf16 bf16x4v __attribute__((ext_vector_type(4)));
typedef float f32x4 __attribute__((ext_vector_type(4)));
typedef int i32x4 __attribute__((ext_vector_type(4)));
typedef int i32x8 __attribute__((ext_vector_type(8)));
typedef unsigned char uchar;

typedef const __attribute__((address_space(1))) void* gptr_t;
typedef __attribute__((address_space(3))) void* lptr_t;

// read MFMA A/B fragment from a [rows x 32] LDS slab with the XOR swizzle
__device__ __forceinline__ bf16x8 read_frag(const __bf16* lds, int rowbase,
                                            int tile, int l) {
  int r = rowbase + tile * 16 + (l & 15);
  int q = l >> 4;
  int blk = q ^ (r & 3);
  return *(const bf16x8*)(lds + r * 32 + blk * 8);
}

// ---------------------------------------------------------------------------
// cast W1, W2 to bf16 (z is consumed f32 directly by mlp_kernel)
__global__ void cast_w_kernel(const float* __restrict__ W1,
                              const float* __restrict__ W2,
                              __bf16* __restrict__ W1b,
                              __bf16* __restrict__ W2b) {
  const int n4w = KDIM * KDIM / 4;   // 16384
  int i = blockIdx.x * blockDim.x + threadIdx.x;
  const float* src;
  __bf16* dst;
  int j;
  if (i < n4w) {
    src = W1; dst = W1b; j = i;
  } else if (i < 2 * n4w) {
    src = W2; dst = W2b; j = i - n4w;
  } else {
    return;
  }
  float4 v = *(const float4*)(src + (size_t)j * 4);
  bf16x4v o;
  o[0] = (__bf16)v.x; o[1] = (__bf16)v.y; o[2] = (__bf16)v.z; o[3] = (__bf16)v.w;
  *(bf16x4v*)(dst + (size_t)j * 4) = o;
}

// fp8 e4m3 byte via the HW cvt
__device__ __forceinline__ uchar fp8_byte(float x) {
#if __has_builtin(__builtin_amdgcn_cvt_pk_fp8_f32)
  int v = __builtin_amdgcn_cvt_pk_fp8_f32(x, 0.f, 0, false);
  return (uchar)(v & 0xFF);
#else
  __hip_fp8_e4m3 qv(x);
  return qv.__x;
#endif
}

// ======== R18 fused MLP: z -> T(LDS) -> H(regs) -> Nq (verbatim) ===========
__global__ __launch_bounds__(256, 2) void mlp_kernel(
    const float* __restrict__ z1, const float* __restrict__ z2,
    const __bf16* __restrict__ W1b, const __bf16* __restrict__ W2b,
    const float* __restrict__ b1, const float* __restrict__ b2,
    uchar* __restrict__ Nq) {
  __shared__ __align__(16) __bf16 Zs[64 * BK];       // 4 KB
  __shared__ __align__(16) __bf16 Ws[KDIM * BK];     // 16 KB
  __shared__ __align__(16) __bf16 Ts[8 * 64 * 32];   // 32 KB (8 ks-slabs)
  __shared__ float ssred[4][64];                     // 1 KB
  __shared__ float invred[64];
  uchar* qbuf = (uchar*)Ts;  // Ts dead after GEMM2; 16 KB reused
  int tid = threadIdx.x;
  int w = tid >> 6, l = tid & 63;
  int q = l >> 4, rx = l & 15;
  int i0 = blockIdx.x * 64;
  int wbcol = w * 64;
  const float* zrow = (i0 < NROWS) ? (z1 + (size_t)i0 * KDIM)
                                   : (z2 + (size_t)(i0 - NROWS) * KDIM);

  auto stageW = [&](const __bf16* Wb, int ks) {
#pragma unroll
    for (int t = 0; t < 4; ++t) {
      int c = w * 4 + t;
      int rr = l >> 2, c2 = l & 3;
      int r = c * 16 + rr;
      int src = c2 ^ (r & 3);
      const __bf16* ga = Wb + (size_t)r * KDIM + ks * BK + src * 8;
      __builtin_amdgcn_global_load_lds((gptr_t)ga, (lptr_t)(Ws + c * 512),
                                       16, 0, 0);
    }
  };
  const int zr = tid >> 2, zblk = tid & 3;
  const int zsrc = zblk ^ (zr & 3);
  auto loadZ = [&](int ks, float4& v0, float4& v1) {
    const float* zp = zrow + (size_t)zr * KDIM + ks * BK + zsrc * 8;
    v0 = *(const float4*)zp;
    v1 = *(const float4*)(zp + 4);
  };

  f32x4 acc[4][4] = {};
  float4 zv0, zv1;
  loadZ(0, zv0, zv1);
  for (int ks = 0; ks < 8; ++ks) {
    __syncthreads();
    bf16x8 zo;
    zo[0] = (__bf16)zv0.x; zo[1] = (__bf16)zv0.y;
    zo[2] = (__bf16)zv0.z; zo[3] = (__bf16)zv0.w;
    zo[4] = (__bf16)zv1.x; zo[5] = (__bf16)zv1.y;
    zo[6] = (__bf16)zv1.z; zo[7] = (__bf16)zv1.w;
    *(bf16x8*)(Zs + zr * 32 + zblk * 8) = zo;
    stageW(W1b, ks);
    if (ks + 1 < 8) loadZ(ks + 1, zv0, zv1);
    __syncthreads();
    bf16x8 aF[4], bF[4];
#pragma unroll
    for (int mi = 0; mi < 4; ++mi) aF[mi] = read_frag(Zs, 0, mi, l);
#pragma unroll
    for (int ni = 0; ni < 4; ++ni) bF[ni] = read_frag(Ws, wbcol, ni, l);
#pragma unroll
    for (int mi = 0; mi < 4; ++mi)
#pragma unroll
      for (int ni = 0; ni < 4; ++ni)
        acc[mi][ni] = __builtin_amdgcn_mfma_f32_16x16x32_bf16(
            aF[mi], bF[ni], acc[mi][ni], 0, 0, 0);
  }

  float bias1[4];
#pragma unroll
  for (int ni = 0; ni < 4; ++ni) bias1[ni] = b1[wbcol + ni * 16 + rx];
#pragma unroll
  for (int mi = 0; mi < 4; ++mi)
#pragma unroll
    for (int ni = 0; ni < 4; ++ni)
#pragma unroll
      for (int v = 0; v < 4; ++v) {
        int row = mi * 16 + q * 4 + v;
        int col = wbcol + ni * 16 + rx;
        float x = acc[mi][ni][v] + bias1[ni];
        x = x > 0.f ? x : (EXP2F(x * LOG2E) - 1.f);  // ELU
        int ks2 = col >> 5, c32 = col & 31;
        Ts[ks2 * 2048 + row * 32 + (((c32 >> 3) ^ (row & 3)) << 3) +
           (col & 7)] = (__bf16)x;
      }

#pragma unroll
  for (int mi = 0; mi < 4; ++mi)
#pragma unroll
    for (int ni = 0; ni < 4; ++ni) acc[mi][ni] = (f32x4){0.f, 0.f, 0.f, 0.f};
  for (int ks = 0; ks < 8; ++ks) {
    __syncthreads();
    stageW(W2b, ks);
    __syncthreads();
    bf16x8 aF[4], bF[4];
#pragma unroll
    for (int mi = 0; mi < 4; ++mi)
      aF[mi] = read_frag(Ts + ks * 2048, 0, mi, l);
#pragma unroll
    for (int ni = 0; ni < 4; ++ni) bF[ni] = read_frag(Ws, wbcol, ni, l);
#pragma unroll
    for (int mi = 0; mi < 4; ++mi)
#pragma unroll
      for (int ni = 0; ni < 4; ++ni)
        acc[mi][ni] = __builtin_amdgcn_mfma_f32_16x16x32_bf16(
            aF[mi], bF[ni], acc[mi][ni], 0, 0, 0);
  }

  float bias2[4];
#pragma unroll
  for (int ni = 0; ni < 4; ++ni) bias2[ni] = b2[wbcol + ni * 16 + rx];
  float ss[4][4] = {};
#pragma unroll
  for (int mi = 0; mi < 4; ++mi)
#pragma unroll
    for (int ni = 0; ni < 4; ++ni)
#pragma unroll
      for (int v = 0; v < 4; ++v) {
        float x = acc[mi][ni][v] + bias2[ni];
        acc[mi][ni][v] = x;
        ss[mi][v] += x * x;
      }
#pragma unroll
  for (int mi = 0; mi < 4; ++mi)
#pragma unroll
    for (int v = 0; v < 4; ++v) {
      float x = ss[mi][v];
      x += __shfl_xor(x, 1, 64);
      x += __shfl_xor(x, 2, 64);
      x += __shfl_xor(x, 4, 64);
      x += __shfl_xor(x, 8, 64);
      if (rx == 0) ssred[w][mi * 16 + q * 4 + v] = x;
    }
  __syncthreads();
  if (tid < 64)
    invred[tid] = rsqrtf(ssred[0][tid] + ssred[1][tid] + ssred[2][tid] +
                         ssred[3][tid]) * SIMSCALE;
  __syncthreads();

#pragma unroll
  for (int mi = 0; mi < 4; ++mi)
#pragma unroll
    for (int v = 0; v < 4; ++v) {
      int row = mi * 16 + q * 4 + v;
      float iv = invred[row];
#pragma unroll
      for (int ni = 0; ni < 4; ++ni)
        qbuf[row * KDIM + wbcol + ni * 16 + rx] =
            fp8_byte(acc[mi][ni][v] * iv);
    }
  __syncthreads();
  size_t base = (size_t)i0 * KDIM;
#pragma unroll
  for (int it = 0; it < 8; ++it) {
    int idx = it * 2048 + tid * 8;
    *(uint2*)(Nq + base + idx) = *(const uint2*)(qbuf + idx);
  }
}

// ======== R20 sim kernel: 64-col tiles, 4 blocks/CU ========================
// Pair p: F (128-col units) < L1=192-p: A=p, J=p+F; else A=191-p, J=F-1.
// G (64-col units) = 2F + half. Slot s: G in [gstart, gend), gstart even.
// Block = 4 waves x (32 A-rows x 64 J-cols). Bs 2x16KB double buffer.
// Off-diag: row-sums (regs, flush on A/half switch) + col-sums (cs4 regs,
// flush deferred one G-tile). Diag 128-tile spans 2 G's, computed whole,
// row-sums only.
__global__ __launch_bounds__(256, 2) void sim_kernel(
    const uchar* __restrict__ Nq, float* __restrict__ Rlow,
    float* __restrict__ Rhigh, float* __restrict__ Dsame,
    float* __restrict__ Dcross) {
  __shared__ __align__(16) uchar Bs[2][64 * KDIM];  // 2 x 16KB
  int tid = threadIdx.x;
  int w = tid >> 6, l = tid & 63;
  int q = l >> 4;
  int rx = l & 15;
  int b = blockIdx.x;
  int p = b >> 4;              // pair index 0..95
  int s = b & 15;              // slot within pair
  const int I1 = p, I2 = NTILE - 1 - p;
  const int L1 = NTILE - I1;   // seg1 length (128-col tiles); 2*193 G total
  int gstart = (s == 0) ? 0 : 26 + (s - 1) * 24;
  int gend = gstart + ((s == 0) ? 26 : 24);
  int warow = w * 32;          // this wave's 32 A-rows

  // staging offsets (XOR swizzle: LDS slot c of row r holds block c^(r&15))
  unsigned off0[4];
#pragma unroll
  for (int t = 0; t < 4; ++t) {
    int ch = w * 4 + t;            // chunk 0..15 (1KB each)
    int r = ch * 4 + q;            // row 0..63
    int src = rx ^ (r & 15);
    off0[t] = (unsigned)(r * KDIM + src * 16);
  }
  auto jtile_of = [&](int F) { return (F < L1) ? (I1 + F) : (F - 1); };
  auto atile_of = [&](int F) { return (F < L1) ? I1 : I2; };
  auto j64_of = [&](int G) { return jtile_of(G >> 1) * 2 + (G & 1); };

  auto stage = [&](int G, int bi) {
    unsigned jo = (unsigned)(j64_of(G) * (64 * KDIM));
#pragma unroll
    for (int t = 0; t < 4; ++t) {
      const uchar* ga = Nq + (size_t)(jo + off0[t]);
      uchar* la = Bs[bi] + (w * 4 + t) * 1024;
      __builtin_amdgcn_global_load_lds((gptr_t)ga, (lptr_t)la, 16, 0, 0);
    }
  };

  // ---- A fragments: aF[mi][hf], 4 x i32x8 = 32 VGPRs ----
  i32x8 aF[2][2];
  auto load_aF = [&](int Atile) {
#pragma unroll
    for (int mi = 0; mi < 2; ++mi) {
      const uchar* ap = Nq +
          (size_t)(Atile * BM + warow + mi * 16 + rx) * KDIM + q * 32;
#pragma unroll
      for (int hf = 0; hf < 2; ++hf)
        aF[mi][hf] = *(const i32x8*)(ap + hf * 128);
    }
  };

  // lane-constant LDS read offsets (rx nj-invariant; nj step = 4096 B)
  int rdo[2][2];
#pragma unroll
  for (int hf = 0; hf < 2; ++hf) {
    int kb = hf * 8 + 2 * q;
    rdo[hf][0] = (kb ^ rx) << 4;
    rdo[hf][1] = ((kb + 1) ^ rx) << 4;
  }

  f32x4 rs4[2] = {};  // row sums for current (A, half(J)) span
  f32x4 cs4[4];       // col partials of the pending G-tile
  int pend = 0;
  float* pendR = nullptr;
  int pendBase = 0;

  auto flushrs = [&](int Atile, int h) {
    float* R = h ? Rhigh : Rlow;
#pragma unroll
    for (int mi = 0; mi < 2; ++mi)
#pragma unroll
      for (int v = 0; v < 4; ++v) {
        float x = rs4[mi][v];
        x += __shfl_xor(x, 1, 64);
        x += __shfl_xor(x, 2, 64);
        x += __shfl_xor(x, 4, 64);
        x += __shfl_xor(x, 8, 64);
        if (rx == 0)
          atomicAdd(&R[Atile * BM + warow + mi * 16 + q * 4 + v], x);
        rs4[mi][v] = 0.f;
      }
  };
  auto flushcs = [&]() {
#pragma unroll
    for (int nj = 0; nj < 4; ++nj) {
      float c = (cs4[nj][0] + cs4[nj][1]) + (cs4[nj][2] + cs4[nj][3]);
      c += __shfl_xor(c, 16, 64);
      c += __shfl_xor(c, 32, 64);
      if (q == 0)
        atomicAdd(&pendR[pendBase + nj * 16 + rx], c);
    }
    pend = 0;
  };

  const f32x4 Z4 = {0.f, 0.f, 0.f, 0.f};

  int Aprev = atile_of(gstart >> 1);
  int hprev = (j64_of(gstart) >= NTILE) ? 1 : 0;  // j64 >= 192
  load_aF(Aprev);
  stage(gstart, 0);

  for (int g = gstart; g < gend; ++g) {
    int bi = (g - gstart) & 1;
    __syncthreads();                      // stage(g) done; prev reads done
    if (g + 1 < gend) stage(g + 1, bi ^ 1);
    if (pend) flushcs();                  // atomics drain a full tile later

    int F = g >> 1, half = g & 1;
    int Atile = atile_of(F);
    int Jt = jtile_of(F);
    int j64 = Jt * 2 + half;
    int h = (j64 >= NTILE) ? 1 : 0;
    if (Atile != Aprev) {          // segment switch (<=1 per block)
      flushrs(Aprev, hprev);
      load_aF(Atile);
      Aprev = Atile;
      hprev = h;
    } else if (h != hprev) {       // half(J) crossing (<=1 per segment)
      flushrs(Aprev, hprev);
      hprev = h;
    }

    bool dsame = (Jt == Atile);                // half of a diagonal tile
    bool dcross = (Jt == Atile + NTILE / 2);
    float* Rcol = (Atile >= NTILE / 2) ? Rhigh : Rlow;

    const uchar* bL = Bs[bi] + (size_t)rx * KDIM;
    const uchar* p00 = bL + rdo[0][0];
    const uchar* p01 = bL + rdo[0][1];
    const uchar* p10 = bL + rdo[1][0];
    const uchar* p11 = bL + rdo[1][1];

#pragma unroll
    for (int nj = 0; nj < 4; ++nj) {
      const int no = nj * 4096;
      i32x8 bF0 = __builtin_shufflevector(*(const i32x4*)(p00 + no),
                                          *(const i32x4*)(p01 + no),
                                          0, 1, 2, 3, 4, 5, 6, 7);
      i32x8 bF1 = __builtin_shufflevector(*(const i32x4*)(p10 + no),
                                          *(const i32x4*)(p11 + no),
                                          0, 1, 2, 3, 4, 5, 6, 7);
      f32x4 acc[2];
#pragma unroll
      for (int mi = 0; mi < 2; ++mi)
        acc[mi] = __builtin_amdgcn_mfma_scale_f32_16x16x128_f8f6f4(
            aF[mi][0], bF0, Z4, 0, 0, 0, 0x7F7F7F7F, 0, 0x7F7F7F7F);
#pragma unroll
      for (int mi = 0; mi < 2; ++mi)
        acc[mi] = __builtin_amdgcn_mfma_scale_f32_16x16x128_f8f6f4(
            aF[mi][1], bF1, acc[mi], 0, 0, 0, 0x7F7F7F7F, 0, 0x7F7F7F7F);
#pragma unroll
      for (int mi = 0; mi < 2; ++mi) {
        f32x4 e4;
        e4[0] = EXP2F(acc[mi][0]);
        e4[1] = EXP2F(acc[mi][1]);
        e4[2] = EXP2F(acc[mi][2]);
        e4[3] = EXP2F(acc[mi][3]);
        rs4[mi] += e4;
        cs4[nj] = (mi == 0) ? e4 : (cs4[nj] + e4);
      }

      if (dsame | dcross) {        // wave-uniform, rare; raw acc probe
        float* D = dsame ? Dsame : Dcross;
#pragma unroll
        for (int mi = 0; mi < 2; ++mi)
#pragma unroll
          for (int v = 0; v < 4; ++v) {
            int li = warow + mi * 16 + q * 4 + v;
            int lj = half * 64 + nj * 16 + rx;
            if (li == lj) D[Atile * BM + li] = acc[mi][v];
          }
      }
    }

    if (!dsame) {  // schedule this G-tile's col-sums for the next iteration
      pend = 1;
      pendR = Rcol;
      pendBase = j64 * 64;
    }
  }

  if (pend) flushcs();
  flushrs(Aprev, hprev);
}

// Dsame/Dcross hold acc = (1/tau)*log2e * s. exp(s/tau) = exp2(acc);
// -2*s = -ln2 * acc.  48 blocks x 256 threads = 12288 rows exactly.
__global__ void finalize1_kernel(const float* __restrict__ Rlow,
                                 const float* __restrict__ Rhigh,
                                 const float* __restrict__ Dsame,
                                 const float* __restrict__ Dcross,
                                 float* __restrict__ partial) {
  __shared__ float red[256];
  int k = blockIdx.x * 256 + threadIdx.x;
  float d1 = Rlow[k] + Rhigh[k] - EXP2F(Dsame[k]);
  float d2 = Rhigh[NROWS + k] + Rlow[NROWS + k] - EXP2F(Dsame[NROWS + k]);
  float acc = 0.5f * (logf(d1) + logf(d2)) - LN2F * Dcross[k];
  red[threadIdx.x] = acc;
  __syncthreads();
  for (int s = 128; s > 0; s >>= 1) {
    if (threadIdx.x < s) red[threadIdx.x] += red[threadIdx.x + s];
    __syncthreads();
  }
  if (threadIdx.x == 0) partial[blockIdx.x] = red[0];
}

__global__ void finalize2_kernel(const float* __restrict__ partial,
                                 float* __restrict__ out) {
  float x = (threadIdx.x < FB) ? partial[threadIdx.x] : 0.f;
#pragma unroll
  for (int s = 32; s > 0; s >>= 1) x += __shfl_down(x, s, 64);
  if (threadIdx.x == 0) out[0] = x / (float)NROWS;
}

// ---------------------------------------------------------------------------
extern "C" void kernel_launch(void* const* d_in, const int* in_sizes, int n_in,
                              void* d_out, int out_size, void* d_ws,
                              size_t ws_size, hipStream_t stream) {
  const float* z1 = (const float*)d_in[0];
  const float* z2 = (const float*)d_in[1];
  const float* W1 = (const float*)d_in[2];
  const float* b1 = (const float*)d_in[3];
  const float* W2 = (const float*)d_in[4];
  const float* b2 = (const float*)d_in[5];
  float* out = (float*)d_out;

  char* ws = (char*)d_ws;
  size_t off = 0;
  auto alloc = [&](size_t bytes) -> void* {
    void* p = ws + off;
    off += (bytes + 255) & ~(size_t)255;
    return p;
  };
  __bf16* W1b  = (__bf16*)alloc((size_t)KDIM * KDIM * 2);
  __bf16* W2b  = (__bf16*)alloc((size_t)KDIM * KDIM * 2);
  uchar*  Nq   = (uchar*)alloc((size_t)TWO_N * KDIM);
  float*  Rlow = (float*)alloc((size_t)TWO_N * 4);   // Rlow+Rhigh contiguous
  float*  Rhigh= (float*)alloc((size_t)TWO_N * 4);
  float*  Dsame= (float*)alloc((size_t)TWO_N * 4);
  float*  Dcross=(float*)alloc((size_t)NROWS * 4);
  float*  partial=(float*)alloc((size_t)FB * 4);

  hipMemsetAsync(Rlow, 0, (size_t)2 * TWO_N * 4, stream);

  int n4w = KDIM * KDIM / 4;    // 16384
  cast_w_kernel<<<(2 * n4w + 255) / 256, 256, 0, stream>>>(W1, W2, W1b, W2b);

  mlp_kernel<<<TWO_N / 64, 256, 0, stream>>>(z1, z2, W1b, W2b, b1, b2, Nq);

  sim_kernel<<<PAIRS * SLOTS, 256, 0, stream>>>(Nq, Rlow, Rhigh, Dsame,
                                                Dcross);
  finalize1_kernel<<<FB, 256, 0, stream>>>(Rlow, Rhigh, Dsame, Dcross, partial);
  finalize2_kernel<<<1, 64, 0, stream>>>(partial, out);
}